// Round 11
// baseline (86.490 us; speedup 1.0000x reference)
//
#include <hip/hip_runtime.h>
#include <cstdint>
#include <cstddef>

typedef short short8 __attribute__((ext_vector_type(8)));
typedef float f32x4 __attribute__((ext_vector_type(4)));

#define NB 2
#define NC 2048
#define NE 1024
#define NH 16
#define ND 64
#define QSZ (NB*NH*NC*ND)   /* 4194304 elems per tensor (q, k, or v) */

typedef const __attribute__((address_space(1))) void GV;
typedef __attribute__((address_space(3))) void LV;

__device__ __forceinline__ unsigned short f32_to_bf16(float f) {
    union { float f; unsigned u; } v; v.f = f;
    return (unsigned short)((v.u + 0x7fffu + ((v.u >> 16) & 1u)) >> 16);
}

// One kernel for all preprocessing: f32->bf16 casts of x / wqkv / wout
// (8192 blocks) + per-batch pad length reduction (2 trailing blocks).
__global__ __launch_bounds__(256) void fused_cast_kernel(
    const float* __restrict__ x, const float* __restrict__ wqkv,
    const float* __restrict__ wout, const void* __restrict__ pad,
    unsigned short* __restrict__ x_bf, unsigned short* __restrict__ wqkv_bf,
    unsigned short* __restrict__ wout_bf, int* __restrict__ lengths)
{
    const int bid = blockIdx.x, tid = threadIdx.x;
    if (bid < 8192) {
        const float* src; unsigned short* dst; int i;
        if (bid < 4096)      { src = x;    dst = x_bf;    i = bid*256 + tid; }
        else if (bid < 7168) { src = wqkv; dst = wqkv_bf; i = (bid-4096)*256 + tid; }
        else                 { src = wout; dst = wout_bf; i = (bid-7168)*256 + tid; }
        float4 v = ((const float4*)src)[i];
        ushort4 o;
        o.x = f32_to_bf16(v.x); o.y = f32_to_bf16(v.y);
        o.z = f32_to_bf16(v.z); o.w = f32_to_bf16(v.w);
        ((ushort4*)dst)[i] = o;
    } else {
        // pad_mask is monotone (arange < length) -> count valids = length.
        const int b = bid - 8192;
        unsigned w0 = ((const unsigned*)pad)[0];
        int cnt = 0;
        for (int i = tid; i < NC; i += 256) {
            int idx = b*NC + i;
            bool valid;
            if (w0 == 1u)               valid = ((const int*)pad)[idx] != 0;
            else if (w0 == 0x3f800000u) valid = ((const float*)pad)[idx] != 0.0f;
            else                        valid = ((const unsigned char*)pad)[idx] != 0;
            cnt += valid ? 1 : 0;
        }
        cnt += __shfl_xor(cnt, 1);  cnt += __shfl_xor(cnt, 2);
        cnt += __shfl_xor(cnt, 4);  cnt += __shfl_xor(cnt, 8);
        cnt += __shfl_xor(cnt, 16); cnt += __shfl_xor(cnt, 32);
        __shared__ int ws_[4];
        if ((tid & 63) == 0) ws_[tid >> 6] = cnt;
        __syncthreads();
        if (tid == 0) lengths[b] = ws_[0] + ws_[1] + ws_[2] + ws_[3];
    }
}

// C = A[M,K] * Bw[N,K]^T + bias.  Tile TM x 128, BK=64, 4 waves, 16x16x32 MFMA.
// TM=128: waves 2x2 own 64x64 (QKV GEMM 3/CU; out-proj R11: 256 blocks 1/CU --
//         2x MFMA per staging-drain vs TM=64, operands L2-hot).
// TM=64:  waves 1x4 own 64x32.
// 1-D grid with bijective XCD swizzle (nwg % 8 == 0).
// EPI=0: f32 out [M,N].
// EPI=1 (TM=128 only): bf16 scatter into qkv.  Q scaled by 0.125*log2e,
//        K: [B,H,C,HD]; V transposed [B,H,HD,C'] keys pi-permuted per 64-tile
//        so attention's PV B-fragment is one conflict-free b128.
//        Pad-length skip: attention never reads K rows / V cols at token
//        index >= roundup64(len_b), so those blocks early-exit (verified R2).
template<int EPI, int TM, int WPE>
__global__ __launch_bounds__(256, WPE) void gemm_bt_kernel(
    const unsigned short* __restrict__ A,
    const unsigned short* __restrict__ Bw,
    const float* __restrict__ bias,
    const int* __restrict__ lengths,
    float* __restrict__ outF,
    unsigned short* __restrict__ outQ,
    int M, int N, int K)
{
    constexpr int NF = (TM == 128) ? 4 : 2;       // n-frags per wave
    constexpr int WCW = 16 * NF;                  // cols per wave
    __shared__ unsigned short As[TM*64];
    __shared__ unsigned short Bs[128*64];
    const int tid = threadIdx.x;
    const int w = tid >> 6, lane = tid & 63;
    const int wr = (TM == 128) ? (w >> 1) : 0;
    const int wc = (TM == 128) ? (w & 1) : w;
    const int g = lane >> 4, lr = lane & 15;
    const int nbx = N >> 7, nwg = gridDim.x;
    const int id = blockIdx.x;
    const int swz = (id & 7) * (nwg >> 3) + (id >> 3);
    const int mBase = (swz / nbx) * TM, nBase = (swz % nbx) * 128;

    if constexpr (EPI == 1) {
        if (nBase >= 1024) {                       // K or V columns only
            const int lb = lengths[mBase >> 11];   // batch = mBase / 2048
            if ((mBase & 2047) >= ((lb + 63) & ~63)) return;
        }
    }

    f32x4 acc[4][NF];
#pragma unroll
    for (int m = 0; m < 4; ++m)
#pragma unroll
        for (int n = 0; n < NF; ++n) acc[m][n] = (f32x4){0.f, 0.f, 0.f, 0.f};

    constexpr int AJ = TM / 32;                   // A staging instrs (1KB each)
    int srow[4], scol[4]; unsigned ldso[4];
#pragma unroll
    for (int j = 0; j < 4; ++j) {
        int o = ((j*4 + w) << 10) + lane*16;
        int row = o >> 7;
        int chunk = ((o >> 4) & 7) ^ (row & 7);
        srow[j] = row; scol[j] = chunk * 8; ldso[j] = (unsigned)((j*4 + w) << 10);
    }

    const int nk = K >> 6;
    for (int kt = 0; kt < nk; ++kt) {
        const int k0 = kt << 6;
#pragma unroll
        for (int j = 0; j < AJ; ++j) {
            const unsigned short* ga = A + (size_t)(mBase + srow[j])*K + (k0 + scol[j]);
            __builtin_amdgcn_global_load_lds((GV*)ga, (LV*)((char*)As + ldso[j]), 16, 0, 0);
        }
#pragma unroll
        for (int j = 0; j < 4; ++j) {
            const unsigned short* gb = Bw + (size_t)(nBase + srow[j])*K + (k0 + scol[j]);
            __builtin_amdgcn_global_load_lds((GV*)gb, (LV*)((char*)Bs + ldso[j]), 16, 0, 0);
        }
        __syncthreads();
#pragma unroll
        for (int ks = 0; ks < 2; ++ks) {
            short8 af[4], bf[NF];
#pragma unroll
            for (int m = 0; m < 4; ++m) {
                int row = wr*64 + m*16 + lr;
                int chunk = (ks*4 + g) ^ (row & 7);
                af[m] = *(const short8*)((const char*)As + row*128 + chunk*16);
            }
#pragma unroll
            for (int n = 0; n < NF; ++n) {
                int row = wc*WCW + n*16 + lr;
                int chunk = (ks*4 + g) ^ (row & 7);
                bf[n] = *(const short8*)((const char*)Bs + row*128 + chunk*16);
            }
#pragma unroll
            for (int m = 0; m < 4; ++m)
#pragma unroll
                for (int n = 0; n < NF; ++n)
                    acc[m][n] = __builtin_amdgcn_mfma_f32_16x16x32_bf16(af[m], bf[n], acc[m][n], 0, 0, 0);
        }
        __syncthreads();
    }

    // Epilogue.  C/D layout: col = lane&15, row = 4*(lane>>4)+reg.
    if constexpr (EPI == 0) {
#pragma unroll
        for (int n = 0; n < NF; ++n) {
            int col = nBase + wc*WCW + n*16 + lr;
            float bv = bias[col];
#pragma unroll
            for (int m = 0; m < 4; ++m) {
                int rowb = mBase + wr*64 + m*16 + 4*g;
#pragma unroll
                for (int r = 0; r < 4; ++r)
                    outF[(size_t)(rowb + r)*N + col] = acc[m][n][r] + bv;
            }
        }
    } else {
        if (nBase >= 2048) {
            // V path: pi-permuted transposed layout, 8B packed stores.
#pragma unroll
            for (int n = 0; n < NF; ++n) {
                int col = nBase + wc*WCW + n*16 + lr;
                float bv = bias[col];
                int hh = (col >> 6) & 15, d = col & 63;
#pragma unroll
                for (int m = 0; m < 4; ++m) {
                    int rowb = mBase + wr*64 + m*16 + 4*g;     // token index, r=0
                    int bb = rowb >> 11, c = rowb & 2047;
                    int cp = (c & ~63) | ((m >> 1) << 5) | (g << 3) | ((m & 1) << 2);
                    size_t base = (((size_t)((4 + bb)*16 + hh))*64 + d)*2048 + cp;
                    float v0 = acc[m][n][0] + bv, v1 = acc[m][n][1] + bv;
                    float v2 = acc[m][n][2] + bv, v3 = acc[m][n][3] + bv;
                    unsigned w0, w1;
                    asm("v_cvt_pk_bf16_f32 %0, %1, %2" : "=v"(w0) : "v"(v0), "v"(v1));
                    asm("v_cvt_pk_bf16_f32 %0, %1, %2" : "=v"(w1) : "v"(v2), "v"(v3));
                    union { unsigned u[2]; uint2 v; } pk2; pk2.u[0] = w0; pk2.u[1] = w1;
                    *(uint2*)(outQ + base) = pk2.v;
                }
            }
        } else {
            // Q/K path (Q pre-scaled into exp2 domain: 0.125 * log2(e)).
#pragma unroll
            for (int n = 0; n < NF; ++n) {
                int col = nBase + wc*WCW + n*16 + lr;
                float bv = bias[col];
                int t = col >> 10, hh = (col >> 6) & 15, d = col & 63;
                float qscale = (t == 0) ? 0.1803368801f : 1.0f;
#pragma unroll
                for (int m = 0; m < 4; ++m) {
                    int rowb = mBase + wr*64 + m*16 + 4*g;
#pragma unroll
                    for (int r = 0; r < 4; ++r) {
                        int row = rowb + r;               // = b*NC + c
                        int bb = row >> 11, c = row & 2047;
                        unsigned short bf16v = f32_to_bf16((acc[m][n][r] + bv) * qscale);
                        size_t idx = ((((size_t)(t*2 + bb))*16 + hh)*2048 + c)*64 + d;
                        outQ[idx] = bf16v;
                    }
                }
            }
        }
    }
}

// Flash attention, causal, swapped-QK^T (one q-row per lane), in-register P.
// One q-tile per block; 1024 blocks = 4/CU; qb<->y permutation gives constant
// per-CU-quad work.  Row-sum l computed ON THE MFMA PIPE via mfma(P, ones).
// R6: folded LDS addressing (2 per-lane bases + immediates), running global
// staging pointers.  R7: raw v_exp_f32 (scores bounded -> identical bits to
// ocml's in-range fast path), edge tile split out of the fast loop, per-lane
// mask threshold thr = min(qg, len-1).  (R5/R10 sync restructures both lost
// to this skeleton: its drains are hidden by 4-blocks/CU TLP.)
__global__ __launch_bounds__(256, 4) void attn_kernel(
    const unsigned short* __restrict__ qkv,
    const int* __restrict__ lengths,
    unsigned short* __restrict__ ctx)
{
    __shared__ unsigned short KVt[4][64*64];   // [0..1]=K dbuf, [2..3]=V dbuf
    const int bh = blockIdx.x;
    const int b = bh >> 4, h = bh & 15;
    const int y = blockIdx.y;
    const int qb = (y < 8) ? 31 - y : (y < 16) ? y - 8 : (y < 24) ? 39 - y : y - 16;
    const int q0 = qb * 64;
    const int len = lengths[b];
    const int nt = min(qb + 1, (len + 63) >> 6);
    const int tid = threadIdx.x, w = tid >> 6, lane = tid & 63;
    const int g = lane >> 4, lr = lane & 15;
    const unsigned short* qp = qkv +          ((size_t)(b*NH + h))*NC*ND;
    const unsigned short* kp = qkv + QSZ    + ((size_t)(b*NH + h))*NC*ND;
    const unsigned short* vp = qkv + 2*QSZ  + ((size_t)(b*NH + h))*ND*NC;  // [d][c-perm]
    const int qw0 = q0 + w*16;

    short8 aq[2];
#pragma unroll
    for (int ks = 0; ks < 2; ++ks)
        aq[ks] = *(const short8*)(qp + (size_t)(qw0 + lr)*ND + ks*32 + 8*g);

    f32x4 oa[4];
#pragma unroll
    for (int n = 0; n < 4; ++n) oa[n] = (f32x4){0.f, 0.f, 0.f, 0.f};
    f32x4 acc_l = (f32x4){0.f, 0.f, 0.f, 0.f};
    union { unsigned u[4]; short8 s; } ones;
    ones.u[0] = ones.u[1] = ones.u[2] = ones.u[3] = 0x3F803F80u;   // bf16 1.0 x8

    // per-lane LDS read bases: frag offset(a,ks) = base_ks + a*2048 (+16384 V)
    const char* kv0 = (char*)KVt + lr*128 + (((g    ) ^ (lr & 7)) << 4);
    const char* kv1 = (char*)KVt + lr*128 + (((4 + g) ^ (lr & 7)) << 4);

    // staging geometry (per-lane invariant) + running global source pointers
    int srw0, sck0, srw1, sck1; unsigned ldso0, ldso1;
    {
        int o0 = (w << 10) + lane*16;
        int r0 = o0 >> 7;
        sck0 = (((o0 >> 4) & 7) ^ (r0 & 7)) * 8; srw0 = r0;
        ldso0 = (unsigned)(w << 10);
        int o1 = ((4 + w) << 10) + lane*16;
        int r1 = o1 >> 7;
        sck1 = (((o1 >> 4) & 7) ^ (r1 & 7)) * 8; srw1 = r1;
        ldso1 = (unsigned)((4 + w) << 10);
    }
    const unsigned short* gk0 = kp + (size_t)srw0*ND + sck0;
    const unsigned short* gk1 = kp + (size_t)srw1*ND + sck1;
    const unsigned short* gv0 = vp + (size_t)srw0*NC + sck0;
    const unsigned short* gv1 = vp + (size_t)srw1*NC + sck1;

#define STAGE(BUF) do {                                                           \
    __builtin_amdgcn_global_load_lds((GV*)gk0, (LV*)((char*)KVt + (BUF)*8192 + ldso0), 16, 0, 0);          \
    __builtin_amdgcn_global_load_lds((GV*)gv0, (LV*)((char*)KVt + 16384 + (BUF)*8192 + ldso0), 16, 0, 0);  \
    __builtin_amdgcn_global_load_lds((GV*)gk1, (LV*)((char*)KVt + (BUF)*8192 + ldso1), 16, 0, 0);          \
    __builtin_amdgcn_global_load_lds((GV*)gv1, (LV*)((char*)KVt + 16384 + (BUF)*8192 + ldso1), 16, 0, 0);  \
    gk0 += 64*ND; gk1 += 64*ND; gv0 += 64; gv1 += 64; } while (0)

    STAGE(0);
    __syncthreads();

    // fast tiles: no masking (keys all causally-valid and < len; see ledger:
    // t < nt-1 => k0+63 <= (nt-1)*64-1 < min(q0, len)).
#pragma unroll 2
    for (int t = 0; t < nt - 1; ++t) {
        STAGE((t + 1) & 1);
        const int buf = t & 1;                      // compile-time under unroll-2

        f32x4 sa[4];
#pragma unroll
        for (int a = 0; a < 4; ++a) sa[a] = (f32x4){0.f, 0.f, 0.f, 0.f};
        __builtin_amdgcn_s_setprio(1);
#pragma unroll
        for (int a = 0; a < 4; ++a) {
            short8 ak = *(const short8*)(kv0 + buf*8192 + a*2048);
            sa[a] = __builtin_amdgcn_mfma_f32_16x16x32_bf16(ak, aq[0], sa[a], 0, 0, 0);
        }
#pragma unroll
        for (int a = 0; a < 4; ++a) {
            short8 ak = *(const short8*)(kv1 + buf*8192 + a*2048);
            sa[a] = __builtin_amdgcn_mfma_f32_16x16x32_bf16(ak, aq[1], sa[a], 0, 0, 0);
        }
        __builtin_amdgcn_s_setprio(0);

        float p[4][4];
#pragma unroll
        for (int a = 0; a < 4; ++a)
#pragma unroll
            for (int r = 0; r < 4; ++r)
                p[a][r] = __builtin_amdgcn_exp2f(sa[a][r]);

        unsigned pw0, pw1, pw2, pw3, pw4, pw5, pw6, pw7;
        asm("v_cvt_pk_bf16_f32 %0, %1, %2" : "=v"(pw0) : "v"(p[0][0]), "v"(p[0][1]));
        asm("v_cvt_pk_bf16_f32 %0, %1, %2" : "=v"(pw1) : "v"(p[0][2]), "v"(p[0][3]));
        asm("v_cvt_pk_bf16_f32 %0, %1, %2" : "=v"(pw2) : "v"(p[1][0]), "v"(p[1][1]));
        asm("v_cvt_pk_bf16_f32 %0, %1, %2" : "=v"(pw3) : "v"(p[1][2]), "v"(p[1][3]));
        asm("v_cvt_pk_bf16_f32 %0, %1, %2" : "=v"(pw4) : "v"(p[2][0]), "v"(p[2][1]));
        asm("v_cvt_pk_bf16_f32 %0, %1, %2" : "=v"(pw5) : "v"(p[2][2]), "v"(p[2][3]));
        asm("v_cvt_pk_bf16_f32 %0, %1, %2" : "=v"(pw6) : "v"(p[3][0]), "v"(p[3][1]));
        asm("v_cvt_pk_bf16_f32 %0, %1, %2" : "=v"(pw7) : "v"(p[3][2]), "v"(p[3][3]));
        union { unsigned u[4]; short8 s; } pu0, pu1;
        pu0.u[0] = pw0; pu0.u[1] = pw1; pu0.u[2] = pw2; pu0.u[3] = pw3;
        pu1.u[0] = pw4; pu1.u[1] = pw5; pu1.u[2] = pw6; pu1.u[3] = pw7;

        __builtin_amdgcn_s_setprio(1);
        acc_l = __builtin_amdgcn_mfma_f32_16x16x32_bf16(pu0.s, ones.s, acc_l, 0, 0, 0);
#pragma unroll
        for (int n = 0; n < 4; ++n) {
            short8 bv = *(const short8*)(kv0 + 16384 + buf*8192 + n*2048);
            oa[n] = __builtin_amdgcn_mfma_f32_16x16x32_bf16(pu0.s, bv, oa[n], 0, 0, 0);
        }
        acc_l = __builtin_amdgcn_mfma_f32_16x16x32_bf16(pu1.s, ones.s, acc_l, 0, 0, 0);
#pragma unroll
        for (int n = 0; n < 4; ++n) {
            short8 bv = *(const short8*)(kv1 + 16384 + buf*8192 + n*2048);
            oa[n] = __builtin_amdgcn_mfma_f32_16x16x32_bf16(pu1.s, bv, oa[n], 0, 0, 0);
        }
        __builtin_amdgcn_s_setprio(0);

        __syncthreads();   // drains vmcnt(0): next tile's stage lands here
    }

    // edge tile t = nt-1 (runtime buf base; masked softmax; no closing barrier)
    {
        const int t = nt - 1;
        const int boff = (t & 1) * 8192;
        const char* k0b = kv0 + boff;
        const char* k1b = kv1 + boff;
        const int thr = min(qw0 + lr, len - 1);     // per-lane key ceiling
        const int kb0 = (t << 6) + 4*g;

        f32x4 sa[4];
#pragma unroll
        for (int a = 0; a < 4; ++a) sa[a] = (f32x4){0.f, 0.f, 0.f, 0.f};
        __builtin_amdgcn_s_setprio(1);
#pragma unroll
        for (int a = 0; a < 4; ++a) {
            short8 ak = *(const short8*)(k0b + a*2048);
            sa[a] = __builtin_amdgcn_mfma_f32_16x16x32_bf16(ak, aq[0], sa[a], 0, 0, 0);
        }
#pragma unroll
        for (int a = 0; a < 4; ++a) {
            short8 ak = *(const short8*)(k1b + a*2048);
            sa[a] = __builtin_amdgcn_mfma_f32_16x16x32_bf16(ak, aq[1], sa[a], 0, 0, 0);
        }
        __builtin_amdgcn_s_setprio(0);

        float p[4][4];
#pragma unroll
        for (int a = 0; a < 4; ++a)
#pragma unroll
            for (int r = 0; r < 4; ++r) {
                int key = kb0 + 16*a + r;
                p[a][r] = (key <= thr) ? __builtin_amdgcn_exp2f(sa[a][r]) : 0.f;
            }

        unsigned pw0, pw1, pw2, pw3, pw4, pw5, pw6, pw7;
        asm("v_cvt_pk_bf16_f32 %0, %1, %2" : "=v"(pw0) : "v"(p[0][0]), "v"(p[0][1]));
        asm("v_cvt_pk_bf16_f32 %0, %1, %2" : "=v"(pw1) : "v"(p[0][2]), "v"(p[0][3]));
        asm("v_cvt_pk_bf16_f32 %0, %1, %2" : "=v"(pw2) : "v"(p[1][0]), "v"(p[1][1]));
        asm("v_cvt_pk_bf16_f32 %0, %1, %2" : "=v"(pw3) : "v"(p[1][2]), "v"(p[1][3]));
        asm("v_cvt_pk_bf16_f32 %0, %1, %2" : "=v"(pw4) : "v"(p[2][0]), "v"(p[2][1]));
        asm("v_cvt_pk_bf16_f32 %0, %1, %2" : "=v"(pw5) : "v"(p[2][2]), "v"(p[2][3]));
        asm("v_cvt_pk_bf16_f32 %0, %1, %2" : "=v"(pw6) : "v"(p[3][0]), "v"(p[3][1]));
        asm("v_cvt_pk_bf16_f32 %0, %1, %2" : "=v"(pw7) : "v"(p[3][2]), "v"(p[3][3]));
        union { unsigned u[4]; short8 s; } pu0, pu1;
        pu0.u[0] = pw0; pu0.u[1] = pw1; pu0.u[2] = pw2; pu0.u[3] = pw3;
        pu1.u[0] = pw4; pu1.u[1] = pw5; pu1.u[2] = pw6; pu1.u[3] = pw7;

        __builtin_amdgcn_s_setprio(1);
        acc_l = __builtin_amdgcn_mfma_f32_16x16x32_bf16(pu0.s, ones.s, acc_l, 0, 0, 0);
#pragma unroll
        for (int n = 0; n < 4; ++n) {
            short8 bv = *(const short8*)(k0b + 16384 + n*2048);
            oa[n] = __builtin_amdgcn_mfma_f32_16x16x32_bf16(pu0.s, bv, oa[n], 0, 0, 0);
        }
        acc_l = __builtin_amdgcn_mfma_f32_16x16x32_bf16(pu1.s, ones.s, acc_l, 0, 0, 0);
#pragma unroll
        for (int n = 0; n < 4; ++n) {
            short8 bv = *(const short8*)(k1b + 16384 + n*2048);
            oa[n] = __builtin_amdgcn_mfma_f32_16x16x32_bf16(pu1.s, bv, oa[n], 0, 0, 0);
        }
        __builtin_amdgcn_s_setprio(0);
    }
#undef STAGE

    // acc_l[r] = l for q = qw0+4g+r (same layout as oa) -> no shuffles.
#pragma unroll
    for (int r = 0; r < 4; ++r) {
        float inv = __builtin_amdgcn_rcpf(acc_l[r]);
        int qg = qw0 + 4*g + r;
        size_t base = ((size_t)b*NC + qg)*NE + h*ND;
#pragma unroll
        for (int n = 0; n < 4; ++n)
            ctx[base + n*16 + lr] = f32_to_bf16(oa[n][r] * inv);
    }
}

extern "C" void kernel_launch(void* const* d_in, const int* in_sizes, int n_in,
                              void* d_out, int out_size, void* d_ws, size_t ws_size,
                              hipStream_t stream)
{
    const float* x    = (const float*)d_in[0];
    const void*  pad  = d_in[1];
    const float* wqkv = (const float*)d_in[2];
    const float* bqkv = (const float*)d_in[3];
    const float* wout = (const float*)d_in[4];
    const float* bout = (const float*)d_in[5];
    float* out = (float*)d_out;

    unsigned short* x_bf    = (unsigned short*)d_ws;
    unsigned short* wqkv_bf = x_bf    + 4194304;
    unsigned short* wout_bf = wqkv_bf + 3145728;
    unsigned short* qkv     = wout_bf + 1048576;
    unsigned short* ctx     = qkv     + 12582912;
    int*            lens    = (int*)(ctx + 4194304);

    fused_cast_kernel<<<8194, 256, 0, stream>>>(x, wqkv, wout, pad,
                                                x_bf, wqkv_bf, wout_bf, lens);

    gemm_bt_kernel<1,128,3><<<768, 256, 0, stream>>>(x_bf, wqkv_bf, bqkv, lens,
                                                     nullptr, qkv, 4096, 3072, 1024);
    attn_kernel<<<dim3(32, 32), 256, 0, stream>>>(qkv, lens, ctx);
    gemm_bt_kernel<0,128,3><<<256, 256, 0, stream>>>(ctx, wout_bf, bout, lens,
                                                     out, nullptr, 4096, 1024, 1024);
}

// Round 12
// 82.580 us; speedup vs baseline: 1.0474x; 1.0474x over previous
//
#include <hip/hip_runtime.h>
#include <cstdint>
#include <cstddef>

typedef short short8 __attribute__((ext_vector_type(8)));
typedef float f32x4 __attribute__((ext_vector_type(4)));

#define NB 2
#define NC 2048
#define NE 1024
#define NH 16
#define ND 64
#define QSZ (NB*NH*NC*ND)   /* 4194304 elems per tensor (q, k, or v) */

typedef const __attribute__((address_space(1))) void GV;
typedef __attribute__((address_space(3))) void LV;

__device__ __forceinline__ unsigned short f32_to_bf16(float f) {
    union { float f; unsigned u; } v; v.f = f;
    return (unsigned short)((v.u + 0x7fffu + ((v.u >> 16) & 1u)) >> 16);
}

// One kernel for all preprocessing: f32->bf16 casts of x / wqkv / wout
// (8192 blocks) + per-batch pad length reduction (2 trailing blocks).
__global__ __launch_bounds__(256) void fused_cast_kernel(
    const float* __restrict__ x, const float* __restrict__ wqkv,
    const float* __restrict__ wout, const void* __restrict__ pad,
    unsigned short* __restrict__ x_bf, unsigned short* __restrict__ wqkv_bf,
    unsigned short* __restrict__ wout_bf, int* __restrict__ lengths)
{
    const int bid = blockIdx.x, tid = threadIdx.x;
    if (bid < 8192) {
        const float* src; unsigned short* dst; int i;
        if (bid < 4096)      { src = x;    dst = x_bf;    i = bid*256 + tid; }
        else if (bid < 7168) { src = wqkv; dst = wqkv_bf; i = (bid-4096)*256 + tid; }
        else                 { src = wout; dst = wout_bf; i = (bid-7168)*256 + tid; }
        float4 v = ((const float4*)src)[i];
        ushort4 o;
        o.x = f32_to_bf16(v.x); o.y = f32_to_bf16(v.y);
        o.z = f32_to_bf16(v.z); o.w = f32_to_bf16(v.w);
        ((ushort4*)dst)[i] = o;
    } else {
        // pad_mask is monotone (arange < length) -> count valids = length.
        const int b = bid - 8192;
        unsigned w0 = ((const unsigned*)pad)[0];
        int cnt = 0;
        for (int i = tid; i < NC; i += 256) {
            int idx = b*NC + i;
            bool valid;
            if (w0 == 1u)               valid = ((const int*)pad)[idx] != 0;
            else if (w0 == 0x3f800000u) valid = ((const float*)pad)[idx] != 0.0f;
            else                        valid = ((const unsigned char*)pad)[idx] != 0;
            cnt += valid ? 1 : 0;
        }
        cnt += __shfl_xor(cnt, 1);  cnt += __shfl_xor(cnt, 2);
        cnt += __shfl_xor(cnt, 4);  cnt += __shfl_xor(cnt, 8);
        cnt += __shfl_xor(cnt, 16); cnt += __shfl_xor(cnt, 32);
        __shared__ int ws_[4];
        if ((tid & 63) == 0) ws_[tid >> 6] = cnt;
        __syncthreads();
        if (tid == 0) lengths[b] = ws_[0] + ws_[1] + ws_[2] + ws_[3];
    }
}

// C = A[M,K] * Bw[N,K]^T + bias.  Tile TM x TN, BK=64, 4 waves, 16x16x32 MFMA.
// TM=128/TN=128: waves 2x2 own 64x64 (QKV GEMM; 3 blocks/CU).
// TM=64/TN=128:  waves 1x4 own 64x32.
// TM=64/TN=64:   waves 1x4 own 64x16 (out-proj R12: 1024 blocks -> 4/CU;
//                inputs L2-resident, kernel is TLP-bound not density-bound).
// 1-D grid with bijective XCD swizzle (nwg % 8 == 0).
// EPI=0: f32 out [M,N].
// EPI=1 (TM=128 only): bf16 scatter into qkv.  Q scaled by 0.125*log2e,
//        K: [B,H,C,HD]; V transposed [B,H,HD,C'] keys pi-permuted per 64-tile
//        so attention's PV B-fragment is one conflict-free b128.
//        Pad-length skip: attention never reads K rows / V cols at token
//        index >= roundup64(len_b), so those blocks early-exit (verified R2).
template<int EPI, int TM, int TN, int WPE>
__global__ __launch_bounds__(256, WPE) void gemm_bt_kernel(
    const unsigned short* __restrict__ A,
    const unsigned short* __restrict__ Bw,
    const float* __restrict__ bias,
    const int* __restrict__ lengths,
    float* __restrict__ outF,
    unsigned short* __restrict__ outQ,
    int M, int N, int K)
{
    constexpr int WCW = (TM == 128) ? TN/2 : TN/4;  // cols per wave
    constexpr int NF  = WCW / 16;                   // n-frags per wave
    constexpr int AJ  = TM / 32;                    // A staging units (1KB)
    constexpr int BJ  = TN / 32;                    // B staging units (1KB)
    __shared__ unsigned short As[TM*64];
    __shared__ unsigned short Bs[TN*64];
    const int tid = threadIdx.x;
    const int w = tid >> 6, lane = tid & 63;
    const int wr = (TM == 128) ? (w >> 1) : 0;
    const int wc = (TM == 128) ? (w & 1) : w;
    const int g = lane >> 4, lr = lane & 15;
    const int nbx = N / TN, nwg = gridDim.x;
    const int id = blockIdx.x;
    const int swz = (id & 7) * (nwg >> 3) + (id >> 3);
    const int mBase = (swz / nbx) * TM, nBase = (swz % nbx) * TN;

    if constexpr (EPI == 1) {
        if (nBase >= 1024) {                       // K or V columns only
            const int lb = lengths[mBase >> 11];   // batch = mBase / 2048
            if ((mBase & 2047) >= ((lb + 63) & ~63)) return;
        }
    }

    f32x4 acc[4][NF];
#pragma unroll
    for (int m = 0; m < 4; ++m)
#pragma unroll
        for (int n = 0; n < NF; ++n) acc[m][n] = (f32x4){0.f, 0.f, 0.f, 0.f};

    int srow[4], scol[4]; unsigned ldso[4];
#pragma unroll
    for (int j = 0; j < 4; ++j) {
        int o = ((j*4 + w) << 10) + lane*16;
        int row = o >> 7;
        int chunk = ((o >> 4) & 7) ^ (row & 7);
        srow[j] = row; scol[j] = chunk * 8; ldso[j] = (unsigned)((j*4 + w) << 10);
    }

    const int nk = K >> 6;
    for (int kt = 0; kt < nk; ++kt) {
        const int k0 = kt << 6;
#pragma unroll
        for (int j = 0; j < AJ; ++j) {
            const unsigned short* ga = A + (size_t)(mBase + srow[j])*K + (k0 + scol[j]);
            __builtin_amdgcn_global_load_lds((GV*)ga, (LV*)((char*)As + ldso[j]), 16, 0, 0);
        }
#pragma unroll
        for (int j = 0; j < BJ; ++j) {
            const unsigned short* gb = Bw + (size_t)(nBase + srow[j])*K + (k0 + scol[j]);
            __builtin_amdgcn_global_load_lds((GV*)gb, (LV*)((char*)Bs + ldso[j]), 16, 0, 0);
        }
        __syncthreads();
#pragma unroll
        for (int ks = 0; ks < 2; ++ks) {
            short8 af[4], bf[NF];
#pragma unroll
            for (int m = 0; m < 4; ++m) {
                int row = wr*64 + m*16 + lr;
                int chunk = (ks*4 + g) ^ (row & 7);
                af[m] = *(const short8*)((const char*)As + row*128 + chunk*16);
            }
#pragma unroll
            for (int n = 0; n < NF; ++n) {
                int row = wc*WCW + n*16 + lr;
                int chunk = (ks*4 + g) ^ (row & 7);
                bf[n] = *(const short8*)((const char*)Bs + row*128 + chunk*16);
            }
#pragma unroll
            for (int m = 0; m < 4; ++m)
#pragma unroll
                for (int n = 0; n < NF; ++n)
                    acc[m][n] = __builtin_amdgcn_mfma_f32_16x16x32_bf16(af[m], bf[n], acc[m][n], 0, 0, 0);
        }
        __syncthreads();
    }

    // Epilogue.  C/D layout: col = lane&15, row = 4*(lane>>4)+reg.
    if constexpr (EPI == 0) {
#pragma unroll
        for (int n = 0; n < NF; ++n) {
            int col = nBase + wc*WCW + n*16 + lr;
            float bv = bias[col];
#pragma unroll
            for (int m = 0; m < 4; ++m) {
                int rowb = mBase + wr*64 + m*16 + 4*g;
#pragma unroll
                for (int r = 0; r < 4; ++r)
                    outF[(size_t)(rowb + r)*N + col] = acc[m][n][r] + bv;
            }
        }
    } else {
        if (nBase >= 2048) {
            // V path: pi-permuted transposed layout, 8B packed stores.
#pragma unroll
            for (int n = 0; n < NF; ++n) {
                int col = nBase + wc*WCW + n*16 + lr;
                float bv = bias[col];
                int hh = (col >> 6) & 15, d = col & 63;
#pragma unroll
                for (int m = 0; m < 4; ++m) {
                    int rowb = mBase + wr*64 + m*16 + 4*g;     // token index, r=0
                    int bb = rowb >> 11, c = rowb & 2047;
                    int cp = (c & ~63) | ((m >> 1) << 5) | (g << 3) | ((m & 1) << 2);
                    size_t base = (((size_t)((4 + bb)*16 + hh))*64 + d)*2048 + cp;
                    float v0 = acc[m][n][0] + bv, v1 = acc[m][n][1] + bv;
                    float v2 = acc[m][n][2] + bv, v3 = acc[m][n][3] + bv;
                    unsigned w0, w1;
                    asm("v_cvt_pk_bf16_f32 %0, %1, %2" : "=v"(w0) : "v"(v0), "v"(v1));
                    asm("v_cvt_pk_bf16_f32 %0, %1, %2" : "=v"(w1) : "v"(v2), "v"(v3));
                    union { unsigned u[2]; uint2 v; } pk2; pk2.u[0] = w0; pk2.u[1] = w1;
                    *(uint2*)(outQ + base) = pk2.v;
                }
            }
        } else {
            // Q/K path (Q pre-scaled into exp2 domain: 0.125 * log2(e)).
#pragma unroll
            for (int n = 0; n < NF; ++n) {
                int col = nBase + wc*WCW + n*16 + lr;
                float bv = bias[col];
                int t = col >> 10, hh = (col >> 6) & 15, d = col & 63;
                float qscale = (t == 0) ? 0.1803368801f : 1.0f;
#pragma unroll
                for (int m = 0; m < 4; ++m) {
                    int rowb = mBase + wr*64 + m*16 + 4*g;
#pragma unroll
                    for (int r = 0; r < 4; ++r) {
                        int row = rowb + r;               // = b*NC + c
                        int bb = row >> 11, c = row & 2047;
                        unsigned short bf16v = f32_to_bf16((acc[m][n][r] + bv) * qscale);
                        size_t idx = ((((size_t)(t*2 + bb))*16 + hh)*2048 + c)*64 + d;
                        outQ[idx] = bf16v;
                    }
                }
            }
        }
    }
}

// Flash attention, causal, swapped-QK^T (one q-row per lane), in-register P.
// One q-tile per block; 1024 blocks = 4/CU; qb<->y permutation gives constant
// per-CU-quad work.  Row-sum l computed ON THE MFMA PIPE via mfma(P, ones).
// R6: folded LDS addressing (2 per-lane bases + immediates), running global
// staging pointers.  R7: raw v_exp_f32 (scores bounded -> identical bits to
// ocml's in-range fast path), edge tile split out of the fast loop, per-lane
// mask threshold thr = min(qg, len-1).  (R5/R10 sync restructures both lost
// to this skeleton: its drains are hidden by 4-blocks/CU TLP.)
__global__ __launch_bounds__(256, 4) void attn_kernel(
    const unsigned short* __restrict__ qkv,
    const int* __restrict__ lengths,
    unsigned short* __restrict__ ctx)
{
    __shared__ unsigned short KVt[4][64*64];   // [0..1]=K dbuf, [2..3]=V dbuf
    const int bh = blockIdx.x;
    const int b = bh >> 4, h = bh & 15;
    const int y = blockIdx.y;
    const int qb = (y < 8) ? 31 - y : (y < 16) ? y - 8 : (y < 24) ? 39 - y : y - 16;
    const int q0 = qb * 64;
    const int len = lengths[b];
    const int nt = min(qb + 1, (len + 63) >> 6);
    const int tid = threadIdx.x, w = tid >> 6, lane = tid & 63;
    const int g = lane >> 4, lr = lane & 15;
    const unsigned short* qp = qkv +          ((size_t)(b*NH + h))*NC*ND;
    const unsigned short* kp = qkv + QSZ    + ((size_t)(b*NH + h))*NC*ND;
    const unsigned short* vp = qkv + 2*QSZ  + ((size_t)(b*NH + h))*ND*NC;  // [d][c-perm]
    const int qw0 = q0 + w*16;

    short8 aq[2];
#pragma unroll
    for (int ks = 0; ks < 2; ++ks)
        aq[ks] = *(const short8*)(qp + (size_t)(qw0 + lr)*ND + ks*32 + 8*g);

    f32x4 oa[4];
#pragma unroll
    for (int n = 0; n < 4; ++n) oa[n] = (f32x4){0.f, 0.f, 0.f, 0.f};
    f32x4 acc_l = (f32x4){0.f, 0.f, 0.f, 0.f};
    union { unsigned u[4]; short8 s; } ones;
    ones.u[0] = ones.u[1] = ones.u[2] = ones.u[3] = 0x3F803F80u;   // bf16 1.0 x8

    // per-lane LDS read bases: frag offset(a,ks) = base_ks + a*2048 (+16384 V)
    const char* kv0 = (char*)KVt + lr*128 + (((g    ) ^ (lr & 7)) << 4);
    const char* kv1 = (char*)KVt + lr*128 + (((4 + g) ^ (lr & 7)) << 4);

    // staging geometry (per-lane invariant) + running global source pointers
    int srw0, sck0, srw1, sck1; unsigned ldso0, ldso1;
    {
        int o0 = (w << 10) + lane*16;
        int r0 = o0 >> 7;
        sck0 = (((o0 >> 4) & 7) ^ (r0 & 7)) * 8; srw0 = r0;
        ldso0 = (unsigned)(w << 10);
        int o1 = ((4 + w) << 10) + lane*16;
        int r1 = o1 >> 7;
        sck1 = (((o1 >> 4) & 7) ^ (r1 & 7)) * 8; srw1 = r1;
        ldso1 = (unsigned)((4 + w) << 10);
    }
    const unsigned short* gk0 = kp + (size_t)srw0*ND + sck0;
    const unsigned short* gk1 = kp + (size_t)srw1*ND + sck1;
    const unsigned short* gv0 = vp + (size_t)srw0*NC + sck0;
    const unsigned short* gv1 = vp + (size_t)srw1*NC + sck1;

#define STAGE(BUF) do {                                                           \
    __builtin_amdgcn_global_load_lds((GV*)gk0, (LV*)((char*)KVt + (BUF)*8192 + ldso0), 16, 0, 0);          \
    __builtin_amdgcn_global_load_lds((GV*)gv0, (LV*)((char*)KVt + 16384 + (BUF)*8192 + ldso0), 16, 0, 0);  \
    __builtin_amdgcn_global_load_lds((GV*)gk1, (LV*)((char*)KVt + (BUF)*8192 + ldso1), 16, 0, 0);          \
    __builtin_amdgcn_global_load_lds((GV*)gv1, (LV*)((char*)KVt + 16384 + (BUF)*8192 + ldso1), 16, 0, 0);  \
    gk0 += 64*ND; gk1 += 64*ND; gv0 += 64; gv1 += 64; } while (0)

    STAGE(0);
    __syncthreads();

    // fast tiles: no masking (keys all causally-valid and < len; see ledger:
    // t < nt-1 => k0+63 <= (nt-1)*64-1 < min(q0, len)).
#pragma unroll 2
    for (int t = 0; t < nt - 1; ++t) {
        STAGE((t + 1) & 1);
        const int buf = t & 1;                      // compile-time under unroll-2

        f32x4 sa[4];
#pragma unroll
        for (int a = 0; a < 4; ++a) sa[a] = (f32x4){0.f, 0.f, 0.f, 0.f};
        __builtin_amdgcn_s_setprio(1);
#pragma unroll
        for (int a = 0; a < 4; ++a) {
            short8 ak = *(const short8*)(kv0 + buf*8192 + a*2048);
            sa[a] = __builtin_amdgcn_mfma_f32_16x16x32_bf16(ak, aq[0], sa[a], 0, 0, 0);
        }
#pragma unroll
        for (int a = 0; a < 4; ++a) {
            short8 ak = *(const short8*)(kv1 + buf*8192 + a*2048);
            sa[a] = __builtin_amdgcn_mfma_f32_16x16x32_bf16(ak, aq[1], sa[a], 0, 0, 0);
        }
        __builtin_amdgcn_s_setprio(0);

        float p[4][4];
#pragma unroll
        for (int a = 0; a < 4; ++a)
#pragma unroll
            for (int r = 0; r < 4; ++r)
                p[a][r] = __builtin_amdgcn_exp2f(sa[a][r]);

        unsigned pw0, pw1, pw2, pw3, pw4, pw5, pw6, pw7;
        asm("v_cvt_pk_bf16_f32 %0, %1, %2" : "=v"(pw0) : "v"(p[0][0]), "v"(p[0][1]));
        asm("v_cvt_pk_bf16_f32 %0, %1, %2" : "=v"(pw1) : "v"(p[0][2]), "v"(p[0][3]));
        asm("v_cvt_pk_bf16_f32 %0, %1, %2" : "=v"(pw2) : "v"(p[1][0]), "v"(p[1][1]));
        asm("v_cvt_pk_bf16_f32 %0, %1, %2" : "=v"(pw3) : "v"(p[1][2]), "v"(p[1][3]));
        asm("v_cvt_pk_bf16_f32 %0, %1, %2" : "=v"(pw4) : "v"(p[2][0]), "v"(p[2][1]));
        asm("v_cvt_pk_bf16_f32 %0, %1, %2" : "=v"(pw5) : "v"(p[2][2]), "v"(p[2][3]));
        asm("v_cvt_pk_bf16_f32 %0, %1, %2" : "=v"(pw6) : "v"(p[3][0]), "v"(p[3][1]));
        asm("v_cvt_pk_bf16_f32 %0, %1, %2" : "=v"(pw7) : "v"(p[3][2]), "v"(p[3][3]));
        union { unsigned u[4]; short8 s; } pu0, pu1;
        pu0.u[0] = pw0; pu0.u[1] = pw1; pu0.u[2] = pw2; pu0.u[3] = pw3;
        pu1.u[0] = pw4; pu1.u[1] = pw5; pu1.u[2] = pw6; pu1.u[3] = pw7;

        __builtin_amdgcn_s_setprio(1);
        acc_l = __builtin_amdgcn_mfma_f32_16x16x32_bf16(pu0.s, ones.s, acc_l, 0, 0, 0);
#pragma unroll
        for (int n = 0; n < 4; ++n) {
            short8 bv = *(const short8*)(kv0 + 16384 + buf*8192 + n*2048);
            oa[n] = __builtin_amdgcn_mfma_f32_16x16x32_bf16(pu0.s, bv, oa[n], 0, 0, 0);
        }
        acc_l = __builtin_amdgcn_mfma_f32_16x16x32_bf16(pu1.s, ones.s, acc_l, 0, 0, 0);
#pragma unroll
        for (int n = 0; n < 4; ++n) {
            short8 bv = *(const short8*)(kv1 + 16384 + buf*8192 + n*2048);
            oa[n] = __builtin_amdgcn_mfma_f32_16x16x32_bf16(pu1.s, bv, oa[n], 0, 0, 0);
        }
        __builtin_amdgcn_s_setprio(0);

        __syncthreads();   // drains vmcnt(0): next tile's stage lands here
    }

    // edge tile t = nt-1 (runtime buf base; masked softmax; no closing barrier)
    {
        const int t = nt - 1;
        const int boff = (t & 1) * 8192;
        const char* k0b = kv0 + boff;
        const char* k1b = kv1 + boff;
        const int thr = min(qw0 + lr, len - 1);     // per-lane key ceiling
        const int kb0 = (t << 6) + 4*g;

        f32x4 sa[4];
#pragma unroll
        for (int a = 0; a < 4; ++a) sa[a] = (f32x4){0.f, 0.f, 0.f, 0.f};
        __builtin_amdgcn_s_setprio(1);
#pragma unroll
        for (int a = 0; a < 4; ++a) {
            short8 ak = *(const short8*)(k0b + a*2048);
            sa[a] = __builtin_amdgcn_mfma_f32_16x16x32_bf16(ak, aq[0], sa[a], 0, 0, 0);
        }
#pragma unroll
        for (int a = 0; a < 4; ++a) {
            short8 ak = *(const short8*)(k1b + a*2048);
            sa[a] = __builtin_amdgcn_mfma_f32_16x16x32_bf16(ak, aq[1], sa[a], 0, 0, 0);
        }
        __builtin_amdgcn_s_setprio(0);

        float p[4][4];
#pragma unroll
        for (int a = 0; a < 4; ++a)
#pragma unroll
            for (int r = 0; r < 4; ++r) {
                int key = kb0 + 16*a + r;
                p[a][r] = (key <= thr) ? __builtin_amdgcn_exp2f(sa[a][r]) : 0.f;
            }

        unsigned pw0, pw1, pw2, pw3, pw4, pw5, pw6, pw7;
        asm("v_cvt_pk_bf16_f32 %0, %1, %2" : "=v"(pw0) : "v"(p[0][0]), "v"(p[0][1]));
        asm("v_cvt_pk_bf16_f32 %0, %1, %2" : "=v"(pw1) : "v"(p[0][2]), "v"(p[0][3]));
        asm("v_cvt_pk_bf16_f32 %0, %1, %2" : "=v"(pw2) : "v"(p[1][0]), "v"(p[1][1]));
        asm("v_cvt_pk_bf16_f32 %0, %1, %2" : "=v"(pw3) : "v"(p[1][2]), "v"(p[1][3]));
        asm("v_cvt_pk_bf16_f32 %0, %1, %2" : "=v"(pw4) : "v"(p[2][0]), "v"(p[2][1]));
        asm("v_cvt_pk_bf16_f32 %0, %1, %2" : "=v"(pw5) : "v"(p[2][2]), "v"(p[2][3]));
        asm("v_cvt_pk_bf16_f32 %0, %1, %2" : "=v"(pw6) : "v"(p[3][0]), "v"(p[3][1]));
        asm("v_cvt_pk_bf16_f32 %0, %1, %2" : "=v"(pw7) : "v"(p[3][2]), "v"(p[3][3]));
        union { unsigned u[4]; short8 s; } pu0, pu1;
        pu0.u[0] = pw0; pu0.u[1] = pw1; pu0.u[2] = pw2; pu0.u[3] = pw3;
        pu1.u[0] = pw4; pu1.u[1] = pw5; pu1.u[2] = pw6; pu1.u[3] = pw7;

        __builtin_amdgcn_s_setprio(1);
        acc_l = __builtin_amdgcn_mfma_f32_16x16x32_bf16(pu0.s, ones.s, acc_l, 0, 0, 0);
#pragma unroll
        for (int n = 0; n < 4; ++n) {
            short8 bv = *(const short8*)(k0b + 16384 + n*2048);
            oa[n] = __builtin_amdgcn_mfma_f32_16x16x32_bf16(pu0.s, bv, oa[n], 0, 0, 0);
        }
        acc_l = __builtin_amdgcn_mfma_f32_16x16x32_bf16(pu1.s, ones.s, acc_l, 0, 0, 0);
#pragma unroll
        for (int n = 0; n < 4; ++n) {
            short8 bv = *(const short8*)(k1b + 16384 + n*2048);
            oa[n] = __builtin_amdgcn_mfma_f32_16x16x32_bf16(pu1.s, bv, oa[n], 0, 0, 0);
        }
        __builtin_amdgcn_s_setprio(0);
    }
#undef STAGE

    // acc_l[r] = l for q = qw0+4g+r (same layout as oa) -> no shuffles.
#pragma unroll
    for (int r = 0; r < 4; ++r) {
        float inv = __builtin_amdgcn_rcpf(acc_l[r]);
        int qg = qw0 + 4*g + r;
        size_t base = ((size_t)b*NC + qg)*NE + h*ND;
#pragma unroll
        for (int n = 0; n < 4; ++n)
            ctx[base + n*16 + lr] = f32_to_bf16(oa[n][r] * inv);
    }
}

extern "C" void kernel_launch(void* const* d_in, const int* in_sizes, int n_in,
                              void* d_out, int out_size, void* d_ws, size_t ws_size,
                              hipStream_t stream)
{
    const float* x    = (const float*)d_in[0];
    const void*  pad  = d_in[1];
    const float* wqkv = (const float*)d_in[2];
    const float* bqkv = (const float*)d_in[3];
    const float* wout = (const float*)d_in[4];
    const float* bout = (const float*)d_in[5];
    float* out = (float*)d_out;

    unsigned short* x_bf    = (unsigned short*)d_ws;
    unsigned short* wqkv_bf = x_bf    + 4194304;
    unsigned short* wout_bf = wqkv_bf + 3145728;
    unsigned short* qkv     = wout_bf + 1048576;
    unsigned short* ctx     = qkv     + 12582912;
    int*            lens    = (int*)(ctx + 4194304);

    fused_cast_kernel<<<8194, 256, 0, stream>>>(x, wqkv, wout, pad,
                                                x_bf, wqkv_bf, wout_bf, lens);

    gemm_bt_kernel<1,128,128,3><<<768, 256, 0, stream>>>(x_bf, wqkv_bf, bqkv, lens,
                                                         nullptr, qkv, 4096, 3072, 1024);
    attn_kernel<<<dim3(32, 32), 256, 0, stream>>>(qkv, lens, ctx);
    gemm_bt_kernel<0,64,64,4><<<1024, 256, 0, stream>>>(ctx, wout_bf, bout, lens,
                                                        out, nullptr, 4096, 1024, 1024);
}